// Round 6
// baseline (572.987 us; speedup 1.0000x reference)
//
#include <hip/hip_runtime.h>
#include <hip/hip_bf16.h>
#include <math.h>

#define WX 32
#define WY 32
#define NTOK 1024
#define TD 1024
#define QKV 512
#define NH 8
#define HD 64
#define TOPK 32
#define BB 64

__device__ __forceinline__ float wred_sum(float v){
  #pragma unroll
  for (int o=32;o;o>>=1) v += __shfl_xor(v,o,64);
  return v;
}
__device__ __forceinline__ float wred_max(float v){
  #pragma unroll
  for (int o=32;o;o>>=1) v = fmaxf(v, __shfl_xor(v,o,64));
  return v;
}
__device__ __forceinline__ float dot4f(float4 a, float4 b){
  return a.x*b.x + a.y*b.y + a.z*b.z + a.w*b.w;
}

// ---------------- K1: per-token LN stats + scorer logits (4 tokens per wave, sw in regs)
__global__ __launch_bounds__(256) void k1_stats(
    const float* __restrict__ x, const float* __restrict__ sw, const float* __restrict__ sb,
    float* __restrict__ mean, float* __restrict__ rstd, float* __restrict__ logit){
  int wave = threadIdx.x >> 6, lane = threadIdx.x & 63;
  int tok0 = blockIdx.x*16 + wave*4;                   // 4096 blocks * 16 tokens
  const float4* sp = (const float4*)sw;
  float4 w0 = sp[lane], w1 = sp[64+lane], w2 = sp[128+lane], w3 = sp[192+lane];
  float sb0 = sb[0];
  float4 cur[4];
  {
    const float4* xp = (const float4*)(x + (size_t)tok0*TD);
    cur[0]=xp[lane]; cur[1]=xp[64+lane]; cur[2]=xp[128+lane]; cur[3]=xp[192+lane];
  }
  #pragma unroll
  for (int i=0;i<4;i++){
    int tok = tok0 + i;
    float4 nxt[4];
    if (i<3){
      const float4* xp = (const float4*)(x + (size_t)(tok+1)*TD);
      nxt[0]=xp[lane]; nxt[1]=xp[64+lane]; nxt[2]=xp[128+lane]; nxt[3]=xp[192+lane];
    }
    float s1=0.f, s2=0.f, sd=0.f;
    s1 += cur[0].x+cur[0].y+cur[0].z+cur[0].w;  s2 += dot4f(cur[0],cur[0]);  sd += dot4f(cur[0],w0);
    s1 += cur[1].x+cur[1].y+cur[1].z+cur[1].w;  s2 += dot4f(cur[1],cur[1]);  sd += dot4f(cur[1],w1);
    s1 += cur[2].x+cur[2].y+cur[2].z+cur[2].w;  s2 += dot4f(cur[2],cur[2]);  sd += dot4f(cur[2],w2);
    s1 += cur[3].x+cur[3].y+cur[3].z+cur[3].w;  s2 += dot4f(cur[3],cur[3]);  sd += dot4f(cur[3],w3);
    s1 = wred_sum(s1); s2 = wred_sum(s2); sd = wred_sum(sd);
    if (lane==0){
      float m = s1*(1.f/1024.f);
      float var = s2*(1.f/1024.f) - m*m;
      mean[tok] = m;
      rstd[tok] = rsqrtf(var + 1e-5f);
      logit[tok] = sd + sb0;
    }
    if (i<3){
      #pragma unroll
      for (int j=0;j<4;j++) cur[j] = nxt[j];
    }
  }
}

// ---------------- K2: per-(b,h) block: argmax, s_n, q[64], u -> gu8/A/C0 (+bias for h==0)
__global__ __launch_bounds__(256) void k2_prep(
    const float* __restrict__ x, const float* __restrict__ logit,
    const float* __restrict__ mean, const float* __restrict__ rstd,
    const float* __restrict__ lng, const float* __restrict__ lnb,
    const float* __restrict__ qkw, const float* __restrict__ qkb,
    const int* __restrict__ relIdx, const float* __restrict__ ub,
    int* __restrict__ selI, float* __restrict__ gu8,
    float* __restrict__ Aw, float* __restrict__ C0w, float* __restrict__ biasArr){
  __shared__ float sn[TD];
  __shared__ float qs[HD];
  __shared__ float red[256];
  __shared__ float redV[4]; __shared__ int redI[4];
  __shared__ int sel_s;
  int b = blockIdx.x >> 3, h = blockIdx.x & 7;
  int t = threadIdx.x, lane = t&63, wave = t>>6;

  // argmax of logits[b, :]
  const float* lg = logit + b*NTOK;
  float bv = -INFINITY; int bi = 0;
  #pragma unroll
  for (int j=0;j<4;j++){ int idx = t*4+j; float v = lg[idx]; if (v > bv){ bv=v; bi=idx; } }
  #pragma unroll
  for (int o=32;o;o>>=1){
    float vv = __shfl_xor(bv,o,64); int ii = __shfl_xor(bi,o,64);
    if (vv > bv || (vv == bv && ii < bi)){ bv=vv; bi=ii; }
  }
  if (lane==0){ redV[wave]=bv; redI[wave]=bi; }
  __syncthreads();
  if (t==0){
    float v = redV[0]; int i = redI[0];
    for (int w=1; w<4; w++){ if (redV[w] > v || (redV[w]==v && redI[w]<i)){ v=redV[w]; i=redI[w]; } }
    sel_s = i;
    if (h==0) selI[b] = i;
  }
  __syncthreads();
  int sel = sel_s;
  float m = mean[b*NTOK+sel], r = rstd[b*NTOK+sel];
  float4 g4 = ((const float4*)lng)[t];
  float4 b4 = ((const float4*)lnb)[t];
  {
    float4 xv = ((const float4*)(x + ((size_t)b*NTOK + sel)*TD))[t];
    float4 s4;
    s4.x = (xv.x-m)*r*g4.x + b4.x;
    s4.y = (xv.y-m)*r*g4.y + b4.y;
    s4.z = (xv.z-m)*r*g4.z + b4.z;
    s4.w = (xv.w-m)*r*g4.w + b4.w;
    ((float4*)sn)[t] = s4;
  }
  __syncthreads();
  // q[c] for this head's 64 rows: 4 threads per row, 256 dims each
  {
    int row = t>>2, part = t&3;
    const float4* wr = (const float4*)(qkw + (size_t)(h*HD+row)*TD + part*256);
    const float4* xp = ((const float4*)sn) + part*64;
    float a0 = 0.f, a1 = 0.f;
    #pragma unroll 4
    for (int j=0;j<64;j+=2){ a0 += dot4f(wr[j], xp[j]); a1 += dot4f(wr[j+1], xp[j+1]); }
    red[t] = a0 + a1;
  }
  __syncthreads();
  if (t < HD) qs[t] = red[t*4]+red[t*4+1]+red[t*4+2]+red[t*4+3] + qkb[h*HD+t];
  __syncthreads();
  // u[d] = sum_c qs[c]*qkw[h*64+c, d]; thread owns dims 4t..4t+3
  float4 accE = make_float4(0.f,0.f,0.f,0.f);
  float4 accO = make_float4(0.f,0.f,0.f,0.f);
  #pragma unroll 4
  for (int c=0;c<HD;c+=2){
    float q0 = qs[c], q1 = qs[c+1];
    float4 w0 = ((const float4*)(qkw + (size_t)(h*HD+c)*TD))[t];
    float4 w1 = ((const float4*)(qkw + (size_t)(h*HD+c+1)*TD))[t];
    accE.x += q0*w0.x; accE.y += q0*w0.y; accE.z += q0*w0.z; accE.w += q0*w0.w;
    accO.x += q1*w1.x; accO.y += q1*w1.y; accO.z += q1*w1.z; accO.w += q1*w1.w;
  }
  float4 acc;
  acc.x = accE.x+accO.x; acc.y = accE.y+accO.y; acc.z = accE.z+accO.z; acc.w = accE.w+accO.w;
  {
    float4 gu;
    gu.x = acc.x*g4.x*0.125f; gu.y = acc.y*g4.y*0.125f;
    gu.z = acc.z*g4.z*0.125f; gu.w = acc.w*g4.w*0.125f;
    ((float4*)(gu8 + ((size_t)(b*NH+h))*TD))[t] = gu;
  }
  float su_p = g4.x*acc.x + g4.y*acc.y + g4.z*acc.z + g4.w*acc.w;
  float bu_p = b4.x*acc.x + b4.y*acc.y + b4.z*acc.z + b4.w*acc.w;
  su_p = wred_sum(su_p); bu_p = wred_sum(bu_p);
  if (lane==0){ red[wave] = su_p; red[8+wave] = bu_p; }
  if (wave==0){
    float qb_p = qs[lane]*qkb[h*HD+lane];
    qb_p = wred_sum(qb_p);
    if (lane==0) red[16] = qb_p;
  }
  __syncthreads();
  if (t==0){
    float s  = red[0]+red[1]+red[2]+red[3];
    float bb = red[8]+red[9]+red[10]+red[11];
    Aw[b*NH+h]  = s*0.125f;
    C0w[b*NH+h] = (bb + red[16])*0.125f;
  }
  if (h==0){
    const int* rp = relIdx + (size_t)sel*NTOK;
    #pragma unroll
    for (int j=0;j<4;j++){
      int n = t*4+j;
      biasArr[b*NTOK+n] = ub[rp[n]];
    }
  }
}

// ---------------- K3: attention logits; gu8 in registers, wave-per-token, LDS-coalesced stores
__global__ __launch_bounds__(256) void k3_attn(
    const float* __restrict__ x, const float* __restrict__ mean, const float* __restrict__ rstd,
    const float* __restrict__ gu8, const float* __restrict__ Aw, const float* __restrict__ C0w,
    const float* __restrict__ biasArr, float* __restrict__ attL){
  __shared__ float sL[NH*65];
  int b = blockIdx.x >> 4;          // 16 blocks per batch
  int chunk = blockIdx.x & 15;      // 64 tokens per block
  int lane = threadIdx.x & 63, wave = threadIdx.x >> 6;

  const float4* gp = (const float4*)(gu8 + (size_t)b*NH*TD);
  float4 G[NH][4];
  #pragma unroll
  for (int h=0;h<NH;h++)
    #pragma unroll
    for (int j=0;j<4;j++)
      G[h][j] = gp[h*256 + j*64 + lane];
  float Ah[NH], Ch[NH];
  #pragma unroll
  for (int h=0;h<NH;h++){ Ah[h] = Aw[b*NH+h]; Ch[h] = C0w[b*NH+h]; }

  const int base = chunk*64 + wave*16;      // this wave's 16 tokens
  float4 cur[4];
  {
    const float4* xp = (const float4*)(x + ((size_t)b*NTOK + base)*TD);
    #pragma unroll
    for (int j=0;j<4;j++) cur[j] = xp[j*64 + lane];
  }
  for (int i=0;i<16;i++){
    int n = base + i;
    int tok = b*NTOK + n;
    float4 nxt[4];
    if (i < 15){
      const float4* xp = (const float4*)(x + (size_t)(tok+1)*TD);
      #pragma unroll
      for (int j=0;j<4;j++) nxt[j] = xp[j*64 + lane];
    }
    float m = mean[tok], r = rstd[tok], bias = biasArr[b*NTOK+n];
    float s[NH];
    #pragma unroll
    for (int h=0;h<NH;h++){
      float a = dot4f(cur[0],G[h][0]) + dot4f(cur[1],G[h][1])
              + dot4f(cur[2],G[h][2]) + dot4f(cur[3],G[h][3]);
      s[h] = wred_sum(a);
    }
    #pragma unroll
    for (int h=0;h<NH;h++){
      if (lane == h)
        sL[h*65 + wave*16 + i] = r*s[h] - r*m*Ah[h] + Ch[h] + bias;
    }
    if (i < 15){
      #pragma unroll
      for (int j=0;j<4;j++) cur[j] = nxt[j];
    }
  }
  __syncthreads();
  #pragma unroll
  for (int hh=0; hh<2; hh++){
    int h = wave + hh*4;
    attL[((size_t)b*NH+h)*NTOK + chunk*64 + lane] = sL[h*65 + lane];
  }
}

// ---------------- K4: per (b,h): softmax -> parallel top-32 -> weighted gather
//                  -> dual GEMV (v_w . xbar + sk_w . x[sel]) -> relu -> t1
__global__ __launch_bounds__(256) void k4_topkv(
    const float* __restrict__ x, const float* __restrict__ mean, const float* __restrict__ rstd,
    const float* __restrict__ lng, const float* __restrict__ lnb,
    const float* __restrict__ vw, const float* __restrict__ vb,
    const float* __restrict__ attL, const int* __restrict__ selI,
    const float* __restrict__ skw, const float* __restrict__ skb,
    float* __restrict__ t1ws){
  __shared__ float redf[4];
  __shared__ float cV[128]; __shared__ int cI[128];
  __shared__ float selV[TOPK]; __shared__ int selIs[TOPK];
  __shared__ float aa[TOPK]; __shared__ float am[TOPK];
  __shared__ float xbar[TD];
  __shared__ float xs[TD];
  __shared__ float red2[256];
  int b = blockIdx.x >> 3, h = blockIdx.x & 7;
  int t = threadIdx.x, lane = t&63, wave = t>>6;

  // preload x[sel] into xs (covered by the barriers below; hides under softmax/topk)
  int sel = selI[b];
  ((float4*)xs)[t] = ((const float4*)(x + ((size_t)b*NTOK + sel)*TD))[t];

  float4 Lv = ((const float4*)(attL + ((size_t)b*NH + h)*NTOK))[t];
  float lm = fmaxf(fmaxf(Lv.x,Lv.y), fmaxf(Lv.z,Lv.w));
  lm = wred_max(lm);
  if (lane==0) redf[wave] = lm;
  __syncthreads();
  float maxL = fmaxf(fmaxf(redf[0],redf[1]), fmaxf(redf[2],redf[3]));
  __syncthreads();
  float ev[4];
  ev[0] = __expf(Lv.x - maxL); ev[1] = __expf(Lv.y - maxL);
  ev[2] = __expf(Lv.z - maxL); ev[3] = __expf(Lv.w - maxL);
  float zp = ev[0]+ev[1]+ev[2]+ev[3];
  zp = wred_sum(zp);
  if (lane==0) redf[wave] = zp;
  __syncthreads();
  float Z = redf[0]+redf[1]+redf[2]+redf[3];
  __syncthreads();

  // per-wave top-32, barrier-free (each wave owns 256 contiguous n)
  for (int k=0;k<TOPK;k++){
    float bv = -1.f; int bi = 1<<20;
    #pragma unroll
    for (int j=0;j<4;j++){ if (ev[j] > bv){ bv = ev[j]; bi = t*4+j; } }
    #pragma unroll
    for (int o=32;o;o>>=1){
      float vv = __shfl_xor(bv,o,64); int ii = __shfl_xor(bi,o,64);
      if (vv > bv || (vv == bv && ii < bi)){ bv=vv; bi=ii; }
    }
    #pragma unroll
    for (int j=0;j<4;j++){ if (bi == t*4+j) ev[j] = -1.f; }
    if (lane==0){ cV[wave*TOPK+k] = bv; cI[wave*TOPK+k] = bi; }
  }
  __syncthreads();
  // parallel rank-based merge: 128 candidates, disjoint indices so ranks unique.
  // rank = #{c' : v' > v  ||  (v'==v && i'<i)}  -- matches lax.top_k stable order
  float selContrib = 0.f;
  if (t < 128){
    float v = cV[t]; int idx = cI[t];
    int rank = 0;
    #pragma unroll 8
    for (int j0=0;j0<32;j0++){
      float4 v4 = ((float4*)cV)[j0];
      int4  i4 = ((int4*)cI)[j0];
      rank += (v4.x > v) || (v4.x==v && i4.x<idx);
      rank += (v4.y > v) || (v4.y==v && i4.y<idx);
      rank += (v4.z > v) || (v4.z==v && i4.z<idx);
      rank += (v4.w > v) || (v4.w==v && i4.w<idx);
    }
    if (rank < TOPK){ selV[rank]=v; selIs[rank]=idx; selContrib = v; }
  }
  float Sp = wred_sum(selContrib);
  if (lane==0) redf[wave] = Sp;
  __syncthreads();
  float S = redf[0]+redf[1]+redf[2]+redf[3];
  float denom = S + 1e-9f*Z;       // == (sum_topk p + 1e-9) * Z
  float W = S/denom;               // sum of renormalized weights
  if (t < TOPK){
    int ni = selIs[t];
    float w = selV[t]/denom;
    float a = w * rstd[b*NTOK+ni];
    aa[t] = a; am[t] = a*mean[b*NTOK+ni];
  }
  __syncthreads();
  float c = 0.f;
  #pragma unroll
  for (int k=0;k<TOPK;k++) c += am[k];

  // xbar = g*(sum_k a_k x[n_k] - c) + b*W
  float4 acc = make_float4(0.f,0.f,0.f,0.f);
  for (int k=0;k<TOPK;k++){
    float a = aa[k];
    float4 xv = ((const float4*)(x + ((size_t)b*NTOK + selIs[k])*TD))[t];
    acc.x += a*xv.x; acc.y += a*xv.y; acc.z += a*xv.z; acc.w += a*xv.w;
  }
  float4 g4 = ((const float4*)lng)[t];
  float4 b4 = ((const float4*)lnb)[t];
  float4 xb;
  xb.x = g4.x*(acc.x - c) + b4.x*W;
  xb.y = g4.y*(acc.y - c) + b4.y*W;
  xb.z = g4.z*(acc.z - c) + b4.z*W;
  xb.w = g4.w*(acc.w - c) + b4.w*W;
  ((float4*)xbar)[t] = xb;
  __syncthreads();

  // t1[row] = relu(v_w[row].xbar + sk_w[row].xs + v_b[row]*W + sk_b[row]) ; row = h*64+co
  int co = t >> 2, part = t & 3;
  int row = h*HD + co;
  {
    const float4* vp = (const float4*)(vw + (size_t)row*TD + part*256);
    const float4* kp = (const float4*)(skw + (size_t)row*TD + part*256);
    const float4* xb2 = ((const float4*)xbar) + part*64;
    const float4* xs2 = ((const float4*)xs) + part*64;
    float a0 = 0.f, a1 = 0.f;
    #pragma unroll 4
    for (int j=0;j<64;j+=2){
      a0 += dot4f(vp[j], xb2[j]) + dot4f(kp[j], xs2[j]);
      a1 += dot4f(vp[j+1], xb2[j+1]) + dot4f(kp[j+1], xs2[j+1]);
    }
    red2[t] = a0 + a1;
  }
  __syncthreads();
  if (part==0){
    float y = red2[t] + red2[t+1] + red2[t+2] + red2[t+3] + vb[row]*W + skb[row];
    t1ws[b*QKV + row] = fmaxf(y, 0.f);
  }
}

// ---------------- K5: fused t2 = t1 @ out_w^T + ob ; out = t2 @ fc_w^T + fcb ; one block per b
__global__ __launch_bounds__(256) void k5bc(
    const float* __restrict__ t1ws, const float* __restrict__ ow,
    const float* __restrict__ ob, const float* __restrict__ fcw,
    const float* __restrict__ fcb, float* __restrict__ out){
  __shared__ float t1s[QKV];
  __shared__ float t2s[QKV];
  __shared__ float redA[4]; __shared__ float redB[4];
  int b = blockIdx.x, t = threadIdx.x, lane = t&63, wave = t>>6;
  if (t < 128) ((float4*)t1s)[t] = ((const float4*)(t1ws + (size_t)b*QKV))[t];
  __syncthreads();
  int r0 = 2*t;
  {
    const float4* w0 = (const float4*)(ow + (size_t)r0*QKV);
    const float4* w1 = (const float4*)(ow + (size_t)(r0+1)*QKV);
    float a0 = 0.f, a1 = 0.f;
    #pragma unroll 8
    for (int j=0;j<128;j++){ float4 x4 = ((float4*)t1s)[j]; a0 += dot4f(w0[j], x4); a1 += dot4f(w1[j], x4); }
    t2s[r0]   = a0 + ob[r0];
    t2s[r0+1] = a1 + ob[r0+1];
  }
  __syncthreads();
  float v0 = t2s[r0], v1 = t2s[r0+1];
  float p0 = v0*fcw[r0] + v1*fcw[r0+1];
  float p1 = v0*fcw[QKV+r0] + v1*fcw[QKV+r0+1];
  p0 = wred_sum(p0); p1 = wred_sum(p1);
  if (lane==0){ redA[wave]=p0; redB[wave]=p1; }
  __syncthreads();
  if (t==0){
    out[b*2+0] = redA[0]+redA[1]+redA[2]+redA[3] + fcb[0];
    out[b*2+1] = redB[0]+redB[1]+redB[2]+redB[3] + fcb[1];
  }
}

extern "C" void kernel_launch(void* const* d_in, const int* in_sizes, int n_in,
                              void* d_out, int out_size, void* d_ws, size_t ws_size,
                              hipStream_t stream) {
  const float* x   = (const float*)d_in[0];
  const float* sw  = (const float*)d_in[1];
  const float* sb  = (const float*)d_in[2];
  const float* lng = (const float*)d_in[3];
  const float* lnb = (const float*)d_in[4];
  const float* qkw = (const float*)d_in[5];
  const float* qkb = (const float*)d_in[6];
  const float* vw  = (const float*)d_in[7];
  const float* vb  = (const float*)d_in[8];
  const float* skw = (const float*)d_in[9];
  const float* skb = (const float*)d_in[10];
  const float* ow  = (const float*)d_in[11];
  const float* ob  = (const float*)d_in[12];
  const float* fcw = (const float*)d_in[13];
  const float* fcb = (const float*)d_in[14];
  const float* ub  = (const float*)d_in[15];
  const int*   ri  = (const int*)d_in[16];
  float* out = (float*)d_out;

  float* wsf     = (float*)d_ws;
  float* logit   = wsf;                    // 65536
  float* mean    = wsf + 65536;            // 65536
  float* rstd    = wsf + 131072;           // 65536
  int*   selI    = (int*)(wsf + 196608);   // 64
  float* gu8     = wsf + 196672;           // 524288
  float* Aw      = wsf + 720960;           // 512
  float* C0w     = wsf + 721472;           // 512
  float* biasArr = wsf + 721984;           // 65536
  float* attL    = wsf + 787520;           // 524288
  float* t1ws    = wsf + 1311808;          // 32768

  k1_stats<<<4096, 256, 0, stream>>>(x, sw, sb, mean, rstd, logit);
  k2_prep<<<BB*NH, 256, 0, stream>>>(x, logit, mean, rstd, lng, lnb, qkw, qkb,
                                     ri, ub, selI, gu8, Aw, C0w, biasArr);
  k3_attn<<<BB*16, 256, 0, stream>>>(x, mean, rstd, gu8, Aw, C0w, biasArr, attL);
  k4_topkv<<<BB*NH, 256, 0, stream>>>(x, mean, rstd, lng, lnb, vw, vb, attL,
                                      selI, skw, skb, t1ws);
  k5bc<<<BB, 256, 0, stream>>>(t1ws, ow, ob, fcw, fcb, out);
}

// Round 7
// 545.369 us; speedup vs baseline: 1.0506x; 1.0506x over previous
//
#include <hip/hip_runtime.h>
#include <hip/hip_bf16.h>
#include <math.h>

#define WX 32
#define WY 32
#define NTOK 1024
#define TD 1024
#define QKV 512
#define NH 8
#define HD 64
#define TOPK 32
#define BB 64

__device__ __forceinline__ float wred_sum(float v){
  #pragma unroll
  for (int o=32;o;o>>=1) v += __shfl_xor(v,o,64);
  return v;
}
__device__ __forceinline__ float wred_max(float v){
  #pragma unroll
  for (int o=32;o;o>>=1) v = fmaxf(v, __shfl_xor(v,o,64));
  return v;
}
__device__ __forceinline__ float dot4f(float4 a, float4 b){
  return a.x*b.x + a.y*b.y + a.z*b.z + a.w*b.w;
}

// ---------------- K1: per-token LN stats + scorer logits (4 tokens per wave, sw in regs)
__global__ __launch_bounds__(256) void k1_stats(
    const float* __restrict__ x, const float* __restrict__ sw, const float* __restrict__ sb,
    float* __restrict__ mean, float* __restrict__ rstd, float* __restrict__ logit){
  int wave = threadIdx.x >> 6, lane = threadIdx.x & 63;
  int tok0 = blockIdx.x*16 + wave*4;                   // 4096 blocks * 16 tokens
  const float4* sp = (const float4*)sw;
  float4 w0 = sp[lane], w1 = sp[64+lane], w2 = sp[128+lane], w3 = sp[192+lane];
  float sb0 = sb[0];
  float4 cur[4];
  {
    const float4* xp = (const float4*)(x + (size_t)tok0*TD);
    cur[0]=xp[lane]; cur[1]=xp[64+lane]; cur[2]=xp[128+lane]; cur[3]=xp[192+lane];
  }
  #pragma unroll
  for (int i=0;i<4;i++){
    int tok = tok0 + i;
    float4 nxt[4];
    if (i<3){
      const float4* xp = (const float4*)(x + (size_t)(tok+1)*TD);
      nxt[0]=xp[lane]; nxt[1]=xp[64+lane]; nxt[2]=xp[128+lane]; nxt[3]=xp[192+lane];
    }
    float s1=0.f, s2=0.f, sd=0.f;
    s1 += cur[0].x+cur[0].y+cur[0].z+cur[0].w;  s2 += dot4f(cur[0],cur[0]);  sd += dot4f(cur[0],w0);
    s1 += cur[1].x+cur[1].y+cur[1].z+cur[1].w;  s2 += dot4f(cur[1],cur[1]);  sd += dot4f(cur[1],w1);
    s1 += cur[2].x+cur[2].y+cur[2].z+cur[2].w;  s2 += dot4f(cur[2],cur[2]);  sd += dot4f(cur[2],w2);
    s1 += cur[3].x+cur[3].y+cur[3].z+cur[3].w;  s2 += dot4f(cur[3],cur[3]);  sd += dot4f(cur[3],w3);
    s1 = wred_sum(s1); s2 = wred_sum(s2); sd = wred_sum(sd);
    if (lane==0){
      float m = s1*(1.f/1024.f);
      float var = s2*(1.f/1024.f) - m*m;
      mean[tok] = m;
      rstd[tok] = rsqrtf(var + 1e-5f);
      logit[tok] = sd + sb0;
    }
    if (i<3){
      #pragma unroll
      for (int j=0;j<4;j++) cur[j] = nxt[j];
    }
  }
}

// ---------------- K2: per-(b,h) block: argmax, s_n, q[64], u -> gu8/A/C0 (+bias for h==0)
__global__ __launch_bounds__(256) void k2_prep(
    const float* __restrict__ x, const float* __restrict__ logit,
    const float* __restrict__ mean, const float* __restrict__ rstd,
    const float* __restrict__ lng, const float* __restrict__ lnb,
    const float* __restrict__ qkw, const float* __restrict__ qkb,
    const int* __restrict__ relIdx, const float* __restrict__ ub,
    int* __restrict__ selI, float* __restrict__ gu8,
    float* __restrict__ Aw, float* __restrict__ C0w, float* __restrict__ biasArr){
  __shared__ float sn[TD];
  __shared__ float qs[HD];
  __shared__ float red[256];
  __shared__ float redV[4]; __shared__ int redI[4];
  __shared__ int sel_s;
  int b = blockIdx.x >> 3, h = blockIdx.x & 7;
  int t = threadIdx.x, lane = t&63, wave = t>>6;

  // argmax of logits[b, :]
  const float* lg = logit + b*NTOK;
  float bv = -INFINITY; int bi = 0;
  #pragma unroll
  for (int j=0;j<4;j++){ int idx = t*4+j; float v = lg[idx]; if (v > bv){ bv=v; bi=idx; } }
  #pragma unroll
  for (int o=32;o;o>>=1){
    float vv = __shfl_xor(bv,o,64); int ii = __shfl_xor(bi,o,64);
    if (vv > bv || (vv == bv && ii < bi)){ bv=vv; bi=ii; }
  }
  if (lane==0){ redV[wave]=bv; redI[wave]=bi; }
  __syncthreads();
  if (t==0){
    float v = redV[0]; int i = redI[0];
    for (int w=1; w<4; w++){ if (redV[w] > v || (redV[w]==v && redI[w]<i)){ v=redV[w]; i=redI[w]; } }
    sel_s = i;
    if (h==0) selI[b] = i;
  }
  __syncthreads();
  int sel = sel_s;
  float m = mean[b*NTOK+sel], r = rstd[b*NTOK+sel];
  float4 g4 = ((const float4*)lng)[t];
  float4 b4 = ((const float4*)lnb)[t];
  {
    float4 xv = ((const float4*)(x + ((size_t)b*NTOK + sel)*TD))[t];
    float4 s4;
    s4.x = (xv.x-m)*r*g4.x + b4.x;
    s4.y = (xv.y-m)*r*g4.y + b4.y;
    s4.z = (xv.z-m)*r*g4.z + b4.z;
    s4.w = (xv.w-m)*r*g4.w + b4.w;
    ((float4*)sn)[t] = s4;
  }
  __syncthreads();
  // q[c] for this head's 64 rows: 4 threads per row, 256 dims each
  {
    int row = t>>2, part = t&3;
    const float4* wr = (const float4*)(qkw + (size_t)(h*HD+row)*TD + part*256);
    const float4* xp = ((const float4*)sn) + part*64;
    float a0 = 0.f, a1 = 0.f;
    #pragma unroll 4
    for (int j=0;j<64;j+=2){ a0 += dot4f(wr[j], xp[j]); a1 += dot4f(wr[j+1], xp[j+1]); }
    red[t] = a0 + a1;
  }
  __syncthreads();
  if (t < HD) qs[t] = red[t*4]+red[t*4+1]+red[t*4+2]+red[t*4+3] + qkb[h*HD+t];
  __syncthreads();
  // u[d] = sum_c qs[c]*qkw[h*64+c, d]; thread owns dims 4t..4t+3
  float4 accE = make_float4(0.f,0.f,0.f,0.f);
  float4 accO = make_float4(0.f,0.f,0.f,0.f);
  #pragma unroll 4
  for (int c=0;c<HD;c+=2){
    float q0 = qs[c], q1 = qs[c+1];
    float4 w0 = ((const float4*)(qkw + (size_t)(h*HD+c)*TD))[t];
    float4 w1 = ((const float4*)(qkw + (size_t)(h*HD+c+1)*TD))[t];
    accE.x += q0*w0.x; accE.y += q0*w0.y; accE.z += q0*w0.z; accE.w += q0*w0.w;
    accO.x += q1*w1.x; accO.y += q1*w1.y; accO.z += q1*w1.z; accO.w += q1*w1.w;
  }
  float4 acc;
  acc.x = accE.x+accO.x; acc.y = accE.y+accO.y; acc.z = accE.z+accO.z; acc.w = accE.w+accO.w;
  {
    float4 gu;
    gu.x = acc.x*g4.x*0.125f; gu.y = acc.y*g4.y*0.125f;
    gu.z = acc.z*g4.z*0.125f; gu.w = acc.w*g4.w*0.125f;
    ((float4*)(gu8 + ((size_t)(b*NH+h))*TD))[t] = gu;
  }
  float su_p = g4.x*acc.x + g4.y*acc.y + g4.z*acc.z + g4.w*acc.w;
  float bu_p = b4.x*acc.x + b4.y*acc.y + b4.z*acc.z + b4.w*acc.w;
  su_p = wred_sum(su_p); bu_p = wred_sum(bu_p);
  if (lane==0){ red[wave] = su_p; red[8+wave] = bu_p; }
  if (wave==0){
    float qb_p = qs[lane]*qkb[h*HD+lane];
    qb_p = wred_sum(qb_p);
    if (lane==0) red[16] = qb_p;
  }
  __syncthreads();
  if (t==0){
    float s  = red[0]+red[1]+red[2]+red[3];
    float bb = red[8]+red[9]+red[10]+red[11];
    Aw[b*NH+h]  = s*0.125f;
    C0w[b*NH+h] = (bb + red[16])*0.125f;
  }
  if (h==0){
    const int* rp = relIdx + (size_t)sel*NTOK;
    #pragma unroll
    for (int j=0;j<4;j++){
      int n = t*4+j;
      biasArr[b*NTOK+n] = ub[rp[n]];
    }
  }
}

// ---------------- K3: attention logits; gu8 in registers, wave-per-token, LDS-coalesced stores
__global__ __launch_bounds__(256) void k3_attn(
    const float* __restrict__ x, const float* __restrict__ mean, const float* __restrict__ rstd,
    const float* __restrict__ gu8, const float* __restrict__ Aw, const float* __restrict__ C0w,
    const float* __restrict__ biasArr, float* __restrict__ attL){
  __shared__ float sL[NH*65];
  int b = blockIdx.x >> 4;          // 16 blocks per batch
  int chunk = blockIdx.x & 15;      // 64 tokens per block
  int lane = threadIdx.x & 63, wave = threadIdx.x >> 6;

  const float4* gp = (const float4*)(gu8 + (size_t)b*NH*TD);
  float4 G[NH][4];
  #pragma unroll
  for (int h=0;h<NH;h++)
    #pragma unroll
    for (int j=0;j<4;j++)
      G[h][j] = gp[h*256 + j*64 + lane];
  float Ah[NH], Ch[NH];
  #pragma unroll
  for (int h=0;h<NH;h++){ Ah[h] = Aw[b*NH+h]; Ch[h] = C0w[b*NH+h]; }

  const int base = chunk*64 + wave*16;      // this wave's 16 tokens
  float4 cur[4];
  {
    const float4* xp = (const float4*)(x + ((size_t)b*NTOK + base)*TD);
    #pragma unroll
    for (int j=0;j<4;j++) cur[j] = xp[j*64 + lane];
  }
  for (int i=0;i<16;i++){
    int n = base + i;
    int tok = b*NTOK + n;
    float4 nxt[4];
    if (i < 15){
      const float4* xp = (const float4*)(x + (size_t)(tok+1)*TD);
      #pragma unroll
      for (int j=0;j<4;j++) nxt[j] = xp[j*64 + lane];
    }
    float m = mean[tok], r = rstd[tok], bias = biasArr[b*NTOK+n];
    float s[NH];
    #pragma unroll
    for (int h=0;h<NH;h++){
      float a = dot4f(cur[0],G[h][0]) + dot4f(cur[1],G[h][1])
              + dot4f(cur[2],G[h][2]) + dot4f(cur[3],G[h][3]);
      s[h] = wred_sum(a);
    }
    #pragma unroll
    for (int h=0;h<NH;h++){
      if (lane == h)
        sL[h*65 + wave*16 + i] = r*s[h] - r*m*Ah[h] + Ch[h] + bias;
    }
    if (i < 15){
      #pragma unroll
      for (int j=0;j<4;j++) cur[j] = nxt[j];
    }
  }
  __syncthreads();
  #pragma unroll
  for (int hh=0; hh<2; hh++){
    int h = wave + hh*4;
    attL[((size_t)b*NH+h)*NTOK + chunk*64 + lane] = sL[h*65 + lane];
  }
}

// ---------------- K4: per (b,h): softmax -> parallel top-32 -> weighted gather -> v_w matvec
__global__ __launch_bounds__(256) void k4_topkv(
    const float* __restrict__ x, const float* __restrict__ mean, const float* __restrict__ rstd,
    const float* __restrict__ lng, const float* __restrict__ lnb,
    const float* __restrict__ vw, const float* __restrict__ vb,
    const float* __restrict__ attL, float* __restrict__ yout){
  __shared__ float redf[4];
  __shared__ float cV[128]; __shared__ int cI[128];
  __shared__ float selV[TOPK]; __shared__ int selIs[TOPK];
  __shared__ float aa[TOPK]; __shared__ float am[TOPK];
  __shared__ float xbar[TD];
  __shared__ float red2[256];
  int b = blockIdx.x >> 3, h = blockIdx.x & 7;
  int t = threadIdx.x, lane = t&63, wave = t>>6;

  float4 Lv = ((const float4*)(attL + ((size_t)b*NH + h)*NTOK))[t];
  float lm = fmaxf(fmaxf(Lv.x,Lv.y), fmaxf(Lv.z,Lv.w));
  lm = wred_max(lm);
  if (lane==0) redf[wave] = lm;
  __syncthreads();
  float maxL = fmaxf(fmaxf(redf[0],redf[1]), fmaxf(redf[2],redf[3]));
  __syncthreads();
  float ev[4];
  ev[0] = __expf(Lv.x - maxL); ev[1] = __expf(Lv.y - maxL);
  ev[2] = __expf(Lv.z - maxL); ev[3] = __expf(Lv.w - maxL);
  float zp = ev[0]+ev[1]+ev[2]+ev[3];
  zp = wred_sum(zp);
  if (lane==0) redf[wave] = zp;
  __syncthreads();
  float Z = redf[0]+redf[1]+redf[2]+redf[3];
  __syncthreads();

  // per-wave top-32, barrier-free (each wave owns 256 contiguous n)
  for (int k=0;k<TOPK;k++){
    float bv = -1.f; int bi = 1<<20;
    #pragma unroll
    for (int j=0;j<4;j++){ if (ev[j] > bv){ bv = ev[j]; bi = t*4+j; } }
    #pragma unroll
    for (int o=32;o;o>>=1){
      float vv = __shfl_xor(bv,o,64); int ii = __shfl_xor(bi,o,64);
      if (vv > bv || (vv == bv && ii < bi)){ bv=vv; bi=ii; }
    }
    #pragma unroll
    for (int j=0;j<4;j++){ if (bi == t*4+j) ev[j] = -1.f; }
    if (lane==0){ cV[wave*TOPK+k] = bv; cI[wave*TOPK+k] = bi; }
  }
  __syncthreads();
  // parallel rank-based merge: 128 candidates, disjoint indices so ranks unique.
  // rank = #{c' : v' > v  ||  (v'==v && i'<i)}  -- matches lax.top_k stable order
  float selContrib = 0.f;
  if (t < 128){
    float v = cV[t]; int idx = cI[t];
    int rank = 0;
    #pragma unroll 8
    for (int j0=0;j0<32;j0++){
      float4 v4 = ((float4*)cV)[j0];
      int4  i4 = ((int4*)cI)[j0];
      rank += (v4.x > v) || (v4.x==v && i4.x<idx);
      rank += (v4.y > v) || (v4.y==v && i4.y<idx);
      rank += (v4.z > v) || (v4.z==v && i4.z<idx);
      rank += (v4.w > v) || (v4.w==v && i4.w<idx);
    }
    if (rank < TOPK){ selV[rank]=v; selIs[rank]=idx; selContrib = v; }
  }
  float Sp = wred_sum(selContrib);
  if (lane==0) redf[wave] = Sp;
  __syncthreads();
  float S = redf[0]+redf[1]+redf[2]+redf[3];
  float denom = S + 1e-9f*Z;       // == (sum_topk p + 1e-9) * Z
  float W = S/denom;               // sum of renormalized weights
  if (t < TOPK){
    int ni = selIs[t];
    float w = selV[t]/denom;
    float a = w * rstd[b*NTOK+ni];
    aa[t] = a; am[t] = a*mean[b*NTOK+ni];
  }
  __syncthreads();
  float c = 0.f;
  #pragma unroll
  for (int k=0;k<TOPK;k++) c += am[k];

  // xbar = g*(sum_k a_k x[n_k] - c) + b*W
  float4 acc = make_float4(0.f,0.f,0.f,0.f);
  for (int k=0;k<TOPK;k++){
    float a = aa[k];
    float4 xv = ((const float4*)(x + ((size_t)b*NTOK + selIs[k])*TD))[t];
    acc.x += a*xv.x; acc.y += a*xv.y; acc.z += a*xv.z; acc.w += a*xv.w;
  }
  float4 g4 = ((const float4*)lng)[t];
  float4 b4 = ((const float4*)lnb)[t];
  float4 xb;
  xb.x = g4.x*(acc.x - c) + b4.x*W;
  xb.y = g4.y*(acc.y - c) + b4.y*W;
  xb.z = g4.z*(acc.z - c) + b4.z*W;
  xb.w = g4.w*(acc.w - c) + b4.w*W;
  ((float4*)xbar)[t] = xb;
  __syncthreads();

  // y[b, h*64+co] = v_w[h*64+co,:] . xbar + v_b*W
  int co = t >> 2, part = t & 3;
  const float4* vp = (const float4*)(vw + (size_t)(h*HD+co)*TD + part*256);
  const float4* xp2 = ((const float4*)xbar) + part*64;
  float a0 = 0.f, a1 = 0.f;
  #pragma unroll 4
  for (int j=0;j<64;j+=2){ a0 += dot4f(vp[j], xp2[j]); a1 += dot4f(vp[j+1], xp2[j+1]); }
  red2[t] = a0 + a1;
  __syncthreads();
  if (part==0){
    float y = red2[t] + red2[t+1] + red2[t+2] + red2[t+3] + vb[h*HD+co]*W;
    yout[b*QKV + h*HD + co] = y;
  }
}

// ---------------- K5a: t1 = relu(y + skip) ; 8 blocks per batch (64 rows each)
__global__ __launch_bounds__(256) void k5a(
    const float* __restrict__ x, const int* __restrict__ selI,
    const float* __restrict__ skw, const float* __restrict__ skb,
    const float* __restrict__ yv, float* __restrict__ t1ws){
  __shared__ float xs[TD];
  __shared__ float red[256];
  int b = blockIdx.x >> 3, chunk = blockIdx.x & 7;
  int t = threadIdx.x;
  int sel = selI[b];
  ((float4*)xs)[t] = ((const float4*)(x + ((size_t)b*NTOK + sel)*TD))[t];
  __syncthreads();
  int row = chunk*64 + (t>>2), part = t&3;
  const float4* wr = (const float4*)(skw + (size_t)row*TD + part*256);
  const float4* xp = ((const float4*)xs) + part*64;
  float a0 = 0.f, a1 = 0.f;
  #pragma unroll 4
  for (int j=0;j<64;j+=2){ a0 += dot4f(wr[j], xp[j]); a1 += dot4f(wr[j+1], xp[j+1]); }
  red[t] = a0 + a1;
  __syncthreads();
  if (part==0){
    float v = red[t]+red[t+1]+red[t+2]+red[t+3];
    t1ws[b*QKV+row] = fmaxf(yv[b*QKV+row] + v + skb[row], 0.f);
  }
}

// ---------------- K5b: t2 = t1 @ out_w^T + ob ; 8 blocks per batch
__global__ __launch_bounds__(256) void k5b(
    const float* __restrict__ t1ws, const float* __restrict__ ow,
    const float* __restrict__ ob, float* __restrict__ t2ws){
  __shared__ float ts[QKV];
  __shared__ float red[256];
  int b = blockIdx.x >> 3, chunk = blockIdx.x & 7;
  int t = threadIdx.x;
  if (t < 128) ((float4*)ts)[t] = ((const float4*)(t1ws + (size_t)b*QKV))[t];
  __syncthreads();
  int row = chunk*64 + (t>>2), part = t&3;
  const float4* wr = (const float4*)(ow + (size_t)row*QKV + part*128);
  const float4* xp = ((const float4*)ts) + part*32;
  float acc = 0.f;
  #pragma unroll
  for (int j=0;j<32;j++) acc += dot4f(wr[j], xp[j]);
  red[t] = acc;
  __syncthreads();
  if (part==0)
    t2ws[b*QKV+row] = red[t]+red[t+1]+red[t+2]+red[t+3] + ob[row];
}

// ---------------- K5c: out = t2 @ fc_w^T + fcb ; one wave per batch
__global__ __launch_bounds__(64) void k5c(
    const float* __restrict__ t2ws, const float* __restrict__ fcw,
    const float* __restrict__ fcb, float* __restrict__ out){
  int b = blockIdx.x, lane = threadIdx.x;
  float a0 = 0.f, a1 = 0.f;
  #pragma unroll
  for (int j=0;j<8;j++){
    int d = j*64 + lane;
    float v = t2ws[(size_t)b*QKV + d];
    a0 += v*fcw[d]; a1 += v*fcw[QKV+d];
  }
  a0 = wred_sum(a0); a1 = wred_sum(a1);
  if (lane==0){ out[b*2+0] = a0 + fcb[0]; out[b*2+1] = a1 + fcb[1]; }
}

extern "C" void kernel_launch(void* const* d_in, const int* in_sizes, int n_in,
                              void* d_out, int out_size, void* d_ws, size_t ws_size,
                              hipStream_t stream) {
  const float* x   = (const float*)d_in[0];
  const float* sw  = (const float*)d_in[1];
  const float* sb  = (const float*)d_in[2];
  const float* lng = (const float*)d_in[3];
  const float* lnb = (const float*)d_in[4];
  const float* qkw = (const float*)d_in[5];
  const float* qkb = (const float*)d_in[6];
  const float* vw  = (const float*)d_in[7];
  const float* vb  = (const float*)d_in[8];
  const float* skw = (const float*)d_in[9];
  const float* skb = (const float*)d_in[10];
  const float* ow  = (const float*)d_in[11];
  const float* ob  = (const float*)d_in[12];
  const float* fcw = (const float*)d_in[13];
  const float* fcb = (const float*)d_in[14];
  const float* ub  = (const float*)d_in[15];
  const int*   ri  = (const int*)d_in[16];
  float* out = (float*)d_out;

  float* wsf     = (float*)d_ws;
  float* logit   = wsf;                    // 65536
  float* mean    = wsf + 65536;            // 65536
  float* rstd    = wsf + 131072;           // 65536
  int*   selI    = (int*)(wsf + 196608);   // 64
  float* gu8     = wsf + 196672;           // 524288
  float* Aw      = wsf + 720960;           // 512
  float* C0w     = wsf + 721472;           // 512
  float* biasArr = wsf + 721984;           // 65536
  float* attL    = wsf + 787520;           // 524288
  float* yv      = wsf + 1311808;          // 32768
  float* t1ws    = wsf + 1344576;          // 32768
  float* t2ws    = wsf + 1377344;          // 32768

  k1_stats<<<4096, 256, 0, stream>>>(x, sw, sb, mean, rstd, logit);
  k2_prep<<<BB*NH, 256, 0, stream>>>(x, logit, mean, rstd, lng, lnb, qkw, qkb,
                                     ri, ub, selI, gu8, Aw, C0w, biasArr);
  k3_attn<<<BB*16, 256, 0, stream>>>(x, mean, rstd, gu8, Aw, C0w, biasArr, attL);
  k4_topkv<<<BB*NH, 256, 0, stream>>>(x, mean, rstd, lng, lnb, vw, vb, attL, yv);
  k5a<<<BB*8, 256, 0, stream>>>(x, selI, skw, skb, yv, t1ws);
  k5b<<<BB*8, 256, 0, stream>>>(t1ws, ow, ob, t2ws);
  k5c<<<BB, 64, 0, stream>>>(t2ws, fcw, fcb, out);
}